// Round 1
// baseline (84.890 us; speedup 1.0000x reference)
//
#include <hip/hip_runtime.h>
#include <math.h>

// Problem constants (from setup_inputs)
#define BB 8
#define HW 4096
#define LTXT 8192
#define GG 4096
#define DD 256

// ws layout (doubles):
// [0,512)      vision chunk products: (b*16+chunk)*4, 8 batches x 16 chunks x quat4
// [512,1536)   text chunk products:   512 + (b*32+chunk)*4
// [1536,2048)  genomic chunk products:1536 + (b*16+chunk)*4
// [2048,3072)  vision-audit block partial sums (1024 blocks)
// [3072,3104)  text-audit block partial sums (32 blocks)

struct Q { double w, x, y, z; };

__device__ inline Q qmul(const Q a, const Q b) {
    Q r;
    r.w = a.w*b.w - a.x*b.x - a.y*b.y - a.z*b.z;
    r.x = a.w*b.x + a.x*b.w + a.y*b.z - a.z*b.y;
    r.y = a.w*b.y - a.x*b.z + a.y*b.w + a.z*b.x;
    r.z = a.w*b.z + a.x*b.y - a.y*b.x + a.z*b.w;
    return r;
}

// Normalize exactly as the f32 reference does: q / (norm_f32 + 1e-8f), then widen.
__device__ inline Q qnormalize_f32(float l0, float l1, float l2, float l3) {
    float n = sqrtf(l0*l0 + l1*l1 + l2*l2 + l3*l3);
    float dn = n + 1e-8f;
    Q q;
    q.w = (double)(l0 / dn);
    q.x = (double)(l1 / dn);
    q.y = (double)(l2 / dn);
    q.z = (double)(l3 / dn);
    return q;
}

__global__ __launch_bounds__(256) void worker_kernel(
    const float* __restrict__ vis, const float* __restrict__ txt, const float* __restrict__ gen,
    const float* __restrict__ Wv, const float* __restrict__ bv,
    const float* __restrict__ Wt, const float* __restrict__ bt,
    const float* __restrict__ Wg, const float* __restrict__ bg,
    double* __restrict__ ws)
{
    __shared__ float sw[1280];   // weights (K*256) + bias (256); max K=4 -> 1280
    __shared__ Q sred[256];      // 8 KB reduce space (also used as double scratch)

    const int t  = threadIdx.x;
    const int id = blockIdx.x;

    if (id < 512) {
        // ---------------- ordered-product chain blocks ----------------
        const float* X; const float* W; const float* bias;
        int K, b, chunk; double* out;
        if (id < 128) {            // vision: 8 batches x 16 chunks
            K = 3; b = id / 16; chunk = id % 16;
            X = vis + (size_t)b * HW * 3; W = Wv; bias = bv;
            out = ws + (size_t)(b * 16 + chunk) * 4;
        } else if (id < 384) {     // text: 8 x 32
            int i2 = id - 128; K = 1; b = i2 / 32; chunk = i2 % 32;
            X = txt + (size_t)b * LTXT; W = Wt; bias = bt;
            out = ws + 512 + (size_t)(b * 32 + chunk) * 4;
        } else {                   // genomic: 8 x 16
            int i2 = id - 384; K = 4; b = i2 / 16; chunk = i2 % 16;
            X = gen + (size_t)b * GG * 4; W = Wg; bias = bg;
            out = ws + 1536 + (size_t)(b * 16 + chunk) * 4;
        }

        for (int idx = t; idx < K * DD; idx += 256) sw[idx] = W[idx];
        for (int idx = t; idx < DD;     idx += 256) sw[K * DD + idx] = bias[idx];
        __syncthreads();

        const int r = chunk * 256 + t;   // one input row per thread = 64 quaternions
        float xv[4];
        #pragma unroll
        for (int k = 0; k < 4; ++k) xv[k] = 0.0f;
        for (int k = 0; k < K; ++k) xv[k] = X[(size_t)r * K + k];

        const float* sb = sw + K * DD;
        Q p = {1.0, 0.0, 0.0, 0.0};
        for (int i = 0; i < 64; ++i) {
            float lat[4];
            #pragma unroll
            for (int c = 0; c < 4; ++c) {
                const int d = 4 * i + c;
                float acc = sb[d];
                for (int k = 0; k < K; ++k) acc = fmaf(xv[k], sw[k * DD + d], acc);
                lat[c] = acc;
            }
            Q q = qnormalize_f32(lat[0], lat[1], lat[2], lat[3]);
            p = qmul(p, q);
        }

        // ordered (non-commutative) tree reduce across 256 threads
        sred[t] = p;
        __syncthreads();
        for (int off = 1; off < 256; off <<= 1) {
            const bool act = ((t & (2 * off - 1)) == 0);
            if (act) { Q o = sred[t + off]; p = qmul(p, o); sred[t] = p; }
            __syncthreads();
        }
        if (t == 0) { out[0] = p.w; out[1] = p.x; out[2] = p.y; out[3] = p.z; }

    } else if (id < 1536) {
        // ---------------- vision holomorphic audit ----------------
        // pair index g over (row r, quaternion i); bias cancels in the batch gradient
        const int aid = id - 512;
        const int g = aid * 256 + t;
        const int r = g >> 6, i = g & 63;
        const int d0 = 4 * i;
        const float wq0 = Wv[d0] + Wv[d0+1] + Wv[d0+2] + Wv[d0+3];
        const float wq1 = Wv[256+d0] + Wv[256+d0+1] + Wv[256+d0+2] + Wv[256+d0+3];
        const float wq2 = Wv[512+d0] + Wv[512+d0+1] + Wv[512+d0+2] + Wv[512+d0+3];

        float vx[8], vy[8], vz[8];
        #pragma unroll
        for (int b = 0; b < 8; ++b) {
            const size_t base = ((size_t)b * HW + r) * 3;
            vx[b] = vis[base]; vy[b] = vis[base+1]; vz[b] = vis[base+2];
        }
        double acc = 0.0;
        #pragma unroll
        for (int b = 0; b < 8; ++b) {
            float gx, gy, gz;
            if (b == 0)      { gx = vx[1]-vx[0];  gy = vy[1]-vy[0];  gz = vz[1]-vz[0]; }
            else if (b == 7) { gx = vx[7]-vx[6];  gy = vy[7]-vy[6];  gz = vz[7]-vz[6]; }
            else             { gx = (vx[b+1]-vx[b-1])*0.5f; gy = (vy[b+1]-vy[b-1])*0.5f; gz = (vz[b+1]-vz[b-1])*0.5f; }
            acc += (double)fabsf(gx*wq0 + gy*wq1 + gz*wq2);
        }
        sred[t].w = acc;
        __syncthreads();
        for (int off = 128; off > 0; off >>= 1) {
            if (t < off) sred[t].w += sred[t + off].w;
            __syncthreads();
        }
        if (t == 0) ws[2048 + aid] = sred[0].w;

    } else {
        // ---------------- text holomorphic audit (gradient factor only) ----------------
        const int aid = id - 1536;
        const int l = aid * 256 + t;     // l in [0, 8192)
        float tv[8];
        #pragma unroll
        for (int b = 0; b < 8; ++b) tv[b] = txt[(size_t)b * LTXT + l];
        double acc = 0.0;
        #pragma unroll
        for (int b = 0; b < 8; ++b) {
            float gb;
            if (b == 0)      gb = tv[1] - tv[0];
            else if (b == 7) gb = tv[7] - tv[6];
            else             gb = (tv[b+1] - tv[b-1]) * 0.5f;
            acc += (double)fabsf(gb);
        }
        sred[t].w = acc;
        __syncthreads();
        for (int off = 128; off > 0; off >>= 1) {
            if (t < off) sred[t].w += sred[t + off].w;
            __syncthreads();
        }
        if (t == 0) ws[3072 + aid] = sred[0].w;
    }
}

__global__ __launch_bounds__(256) void finalize_kernel(
    const float* __restrict__ vis, const float* __restrict__ txt, const float* __restrict__ gen,
    const float* __restrict__ Wv, const float* __restrict__ bv,
    const float* __restrict__ Wt, const float* __restrict__ bt,
    const float* __restrict__ Wg, const float* __restrict__ bg,
    const double* __restrict__ ws, float* __restrict__ out)
{
    __shared__ double sphi[24];     // phi[m][b], m: 0=v 1=t 2=g
    __shared__ double sred[256];
    __shared__ double s_sumv, s_sumt, s_sumw;
    const int t = threadIdx.x;

    if (t < 24) {
        const int m = t >> 3, b = t & 7;
        const int nch = (m == 1) ? 32 : 16;
        const double* base = ws + ((m == 0) ? 0 : (m == 1) ? 512 : 1536) + (size_t)b * nch * 4;
        Q p = {base[0], base[1], base[2], base[3]};
        for (int c = 1; c < nch; ++c) {
            Q o = {base[c*4], base[c*4+1], base[c*4+2], base[c*4+3]};
            p = qmul(p, o);
        }
        // q0 = normalized first quaternion of the path
        float lat[4];
        if (m == 0) {
            const float x0 = vis[(size_t)b*HW*3], x1 = vis[(size_t)b*HW*3+1], x2 = vis[(size_t)b*HW*3+2];
            #pragma unroll
            for (int c = 0; c < 4; ++c)
                lat[c] = fmaf(x0, Wv[c], fmaf(x1, Wv[256+c], fmaf(x2, Wv[512+c], bv[c])));
        } else if (m == 1) {
            const float x0 = txt[(size_t)b*LTXT];
            #pragma unroll
            for (int c = 0; c < 4; ++c) lat[c] = fmaf(x0, Wt[c], bt[c]);
        } else {
            const float x0 = gen[(size_t)b*GG*4], x1 = gen[(size_t)b*GG*4+1],
                        x2 = gen[(size_t)b*GG*4+2], x3 = gen[(size_t)b*GG*4+3];
            #pragma unroll
            for (int c = 0; c < 4; ++c)
                lat[c] = fmaf(x0, Wg[c], fmaf(x1, Wg[256+c], fmaf(x2, Wg[512+c], fmaf(x3, Wg[768+c], bg[c]))));
        }
        Q q0 = qnormalize_f32(lat[0], lat[1], lat[2], lat[3]);
        p = qmul(p, q0);
        double w = p.w;
        if (w > 1.0) w = 1.0;
        if (w < -1.0) w = -1.0;
        sphi[t] = 2.0 * acos(w);
    }
    __syncthreads();

    // sum of 1024 vision-audit partials
    double a = 0.0;
    for (int idx = t; idx < 1024; idx += 256) a += ws[2048 + idx];
    sred[t] = a; __syncthreads();
    for (int off = 128; off > 0; off >>= 1) { if (t < off) sred[t] += sred[t+off]; __syncthreads(); }
    if (t == 0) s_sumv = sred[0];
    __syncthreads();

    // sum of 32 text-audit partials
    sred[t] = (t < 32) ? ws[3072 + t] : 0.0; __syncthreads();
    for (int off = 128; off > 0; off >>= 1) { if (t < off) sred[t] += sred[t+off]; __syncthreads(); }
    if (t == 0) s_sumt = sred[0];
    __syncthreads();

    // sum_i |wtq_i|, wtq_i = sum of 4 consecutive Wt entries
    double aw = 0.0;
    if (t < 64) {
        const int d0 = 4 * t;
        aw = (double)fabsf(Wt[d0] + Wt[d0+1] + Wt[d0+2] + Wt[d0+3]);
    }
    sred[t] = aw; __syncthreads();
    for (int off = 128; off > 0; off >>= 1) { if (t < off) sred[t] += sred[t+off]; __syncthreads(); }
    if (t == 0) s_sumw = sred[0];
    __syncthreads();

    if (t == 0) {
        double mv = 0.0, mt = 0.0;
        for (int b = 0; b < 8; ++b) { mv += sphi[b]; mt += sphi[8 + b]; }
        mv /= 8.0; mt /= 8.0;
        const double interf = fabs(mv - mt);
        for (int b = 0; b < 8; ++b)
            out[b] = (float)exp(-fabs(sphi[16 + b] - interf));
        out[8]  = (float)interf;
        out[9]  = (float)(s_sumv / 2097152.0);            // 8 * 262144
        out[10] = (float)(s_sumt * s_sumw / 4194304.0);   // 8 * 524288
    }
}

extern "C" void kernel_launch(void* const* d_in, const int* in_sizes, int n_in,
                              void* d_out, int out_size, void* d_ws, size_t ws_size,
                              hipStream_t stream) {
    (void)in_sizes; (void)n_in; (void)out_size; (void)ws_size;
    const float* vis = (const float*)d_in[0];
    const float* txt = (const float*)d_in[1];
    const float* gen = (const float*)d_in[2];
    const float* Wv  = (const float*)d_in[3];
    const float* bv  = (const float*)d_in[4];
    const float* Wt  = (const float*)d_in[5];
    const float* bt  = (const float*)d_in[6];
    const float* Wg  = (const float*)d_in[7];
    const float* bg  = (const float*)d_in[8];
    double* ws = (double*)d_ws;
    float* out = (float*)d_out;

    hipLaunchKernelGGL(worker_kernel, dim3(1568), dim3(256), 0, stream,
                       vis, txt, gen, Wv, bv, Wt, bt, Wg, bg, ws);
    hipLaunchKernelGGL(finalize_kernel, dim3(1), dim3(256), 0, stream,
                       vis, txt, gen, Wv, bv, Wt, bt, Wg, bg, ws, out);
}

// Round 2
// 42.540 us; speedup vs baseline: 1.9955x; 1.9955x over previous
//
#include <hip/hip_runtime.h>
#include <math.h>

// Problem constants (from setup_inputs)
#define BB 8
#define HW 4096
#define LTXT 8192
#define GG 4096
#define DD 256

// Grid layout (worker): 560 blocks x 256 threads
//   [0,128)    vision chain blocks:  b = id/16,        chunk = id%16   (256 rows each)
//   [128,384)  text chain blocks:    b = (id-128)/32,  chunk = %32
//   [384,512)  genomic chain blocks: b = (id-384)/16,  chunk = %16
//   [512,528)  vision audit blocks (thread = row)
//   [528,560)  text audit blocks   (thread = position l)
//
// ws layout:
//   floats  [0,512)    vision chunk products  (128 blocks x quat4)
//           [512,1536) text chunk products    (256 blocks x quat4)
//           [1536,2048) genomic chunk products (128 blocks x quat4)
//   doubles at byte offset 8192: [0,16) vision-audit partials, [16,48) text-audit partials

struct QF { float w, x, y, z; };
struct QD { double w, x, y, z; };

__device__ inline QF qmulf(const QF a, const QF b) {
    QF r;
    r.w = fmaf(a.w, b.w, -fmaf(a.x, b.x, fmaf(a.y, b.y, a.z * b.z)));
    r.x = fmaf(a.w, b.x, fmaf(a.x, b.w, fmaf(a.y, b.z, -(a.z * b.y))));
    r.y = fmaf(a.w, b.y, fmaf(a.y, b.w, fmaf(a.z, b.x, -(a.x * b.z))));
    r.z = fmaf(a.w, b.z, fmaf(a.x, b.y, fmaf(a.z, b.w, -(a.y * b.x))));
    return r;
}

__device__ inline QD qmuld(const QD a, const QD b) {
    QD r;
    r.w = a.w*b.w - a.x*b.x - a.y*b.y - a.z*b.z;
    r.x = a.w*b.x + a.x*b.w + a.y*b.z - a.z*b.y;
    r.y = a.w*b.y - a.x*b.z + a.y*b.w + a.z*b.x;
    r.z = a.w*b.z + a.x*b.y - a.y*b.x + a.z*b.w;
    return r;
}

// Normalize exactly as the f32 reference: q / (norm_f32 + 1e-8f).
__device__ inline QF qnorm_f32(float l0, float l1, float l2, float l3) {
    float n = sqrtf(fmaf(l0, l0, fmaf(l1, l1, fmaf(l2, l2, l3 * l3))));
    float inv = 1.0f / (n + 1e-8f);
    QF q = { l0 * inv, l1 * inv, l2 * inv, l3 * inv };
    return q;
}

template<int K>
__device__ void chain_block(const float* __restrict__ X, const float* __restrict__ W,
                            const float* __restrict__ bias, int rowBase,
                            float* __restrict__ out4, float* sprod /* LDS, >=16 floats */)
{
    const int t = threadIdx.x;
    const int r = rowBase + t;            // this thread's input row = 64 consecutive quats
    float xv[K];
    #pragma unroll
    for (int k = 0; k < K; ++k) xv[k] = X[(size_t)r * K + k];

    QF p = {1.0f, 0.0f, 0.0f, 0.0f};
    for (int i = 0; i < 64; ++i) {
        // weight/bias addresses are wave-uniform -> one broadcast L1 transaction each
        const float4 b4 = *(const float4*)(bias + 4 * i);
        float l0 = b4.x, l1 = b4.y, l2 = b4.z, l3 = b4.w;
        #pragma unroll
        for (int k = 0; k < K; ++k) {
            const float4 w4 = *(const float4*)(W + k * DD + 4 * i);
            l0 = fmaf(xv[k], w4.x, l0);
            l1 = fmaf(xv[k], w4.y, l1);
            l2 = fmaf(xv[k], w4.z, l2);
            l3 = fmaf(xv[k], w4.w, l3);
        }
        p = qmulf(p, qnorm_f32(l0, l1, l2, l3));
    }

    // ordered (non-commutative) wave reduce: lower lane's product goes on the left
    const int lane = t & 63;
    #pragma unroll
    for (int s = 1; s < 64; s <<= 1) {
        QF o;
        o.w = __shfl_xor(p.w, s, 64);
        o.x = __shfl_xor(p.x, s, 64);
        o.y = __shfl_xor(p.y, s, 64);
        o.z = __shfl_xor(p.z, s, 64);
        const bool hi = (lane & s) != 0;
        QF a = hi ? o : p;
        QF b = hi ? p : o;
        p = qmulf(a, b);
    }

    const int w = t >> 6;
    if (lane == 0) { sprod[w*4+0] = p.w; sprod[w*4+1] = p.x; sprod[w*4+2] = p.y; sprod[w*4+3] = p.z; }
    __syncthreads();
    if (t == 0) {
        QF pp = { sprod[0], sprod[1], sprod[2], sprod[3] };
        #pragma unroll
        for (int wv = 1; wv < 4; ++wv) {
            QF o = { sprod[wv*4+0], sprod[wv*4+1], sprod[wv*4+2], sprod[wv*4+3] };
            pp = qmulf(pp, o);
        }
        out4[0] = pp.w; out4[1] = pp.x; out4[2] = pp.y; out4[3] = pp.z;
    }
}

__global__ __launch_bounds__(256) void worker_kernel(
    const float* __restrict__ vis, const float* __restrict__ txt, const float* __restrict__ gen,
    const float* __restrict__ Wv, const float* __restrict__ bv,
    const float* __restrict__ Wt, const float* __restrict__ bt,
    const float* __restrict__ Wg, const float* __restrict__ bg,
    float* __restrict__ wsf, double* __restrict__ dws)
{
    __shared__ double sred[256];          // 2 KB; also aliased as float scratch for chain
    float* sprod = (float*)sred;

    const int t  = threadIdx.x;
    const int id = blockIdx.x;

    if (id < 128) {
        const int b = id >> 4, chunk = id & 15;
        chain_block<3>(vis + (size_t)b * HW * 3, Wv, bv, chunk * 256,
                       wsf + (size_t)id * 4, sprod);
    } else if (id < 384) {
        const int i2 = id - 128;
        const int b = i2 >> 5, chunk = i2 & 31;
        chain_block<1>(txt + (size_t)b * LTXT, Wt, bt, chunk * 256,
                       wsf + 512 + (size_t)i2 * 4, sprod);
    } else if (id < 512) {
        const int i2 = id - 384;
        const int b = i2 >> 4, chunk = i2 & 15;
        chain_block<4>(gen + (size_t)b * GG * 4, Wg, bg, chunk * 256,
                       wsf + 1536 + (size_t)i2 * 4, sprod);
    } else if (id < 528) {
        // ---------------- vision holomorphic audit: thread = row ----------------
        const int aid = id - 512;
        const int r = aid * 256 + t;      // 0..4095
        float gx[8], gy[8], gz[8];
        {
            float vx[8], vy[8], vz[8];
            #pragma unroll
            for (int b = 0; b < 8; ++b) {
                const size_t base = ((size_t)b * HW + r) * 3;
                vx[b] = vis[base]; vy[b] = vis[base+1]; vz[b] = vis[base+2];
            }
            #pragma unroll
            for (int b = 0; b < 8; ++b) {
                if (b == 0)      { gx[b] = vx[1]-vx[0];  gy[b] = vy[1]-vy[0];  gz[b] = vz[1]-vz[0]; }
                else if (b == 7) { gx[b] = vx[7]-vx[6];  gy[b] = vy[7]-vy[6];  gz[b] = vz[7]-vz[6]; }
                else             { gx[b] = (vx[b+1]-vx[b-1])*0.5f; gy[b] = (vy[b+1]-vy[b-1])*0.5f; gz[b] = (vz[b+1]-vz[b-1])*0.5f; }
            }
        }
        double acc = 0.0;
        for (int i = 0; i < 64; ++i) {
            const float4 a0 = *(const float4*)(Wv + 4*i);
            const float4 a1 = *(const float4*)(Wv + DD + 4*i);
            const float4 a2 = *(const float4*)(Wv + 2*DD + 4*i);
            const float wq0 = a0.x + a0.y + a0.z + a0.w;
            const float wq1 = a1.x + a1.y + a1.z + a1.w;
            const float wq2 = a2.x + a2.y + a2.z + a2.w;
            #pragma unroll
            for (int b = 0; b < 8; ++b)
                acc += (double)fabsf(fmaf(gx[b], wq0, fmaf(gy[b], wq1, gz[b] * wq2)));
        }
        sred[t] = acc;
        __syncthreads();
        for (int off = 128; off > 0; off >>= 1) {
            if (t < off) sred[t] += sred[t + off];
            __syncthreads();
        }
        if (t == 0) dws[aid] = sred[0];
    } else {
        // ---------------- text holomorphic audit (gradient factor) ----------------
        const int aid = id - 528;
        const int l = aid * 256 + t;      // 0..8191
        float tv[8];
        #pragma unroll
        for (int b = 0; b < 8; ++b) tv[b] = txt[(size_t)b * LTXT + l];
        double acc = 0.0;
        #pragma unroll
        for (int b = 0; b < 8; ++b) {
            float gb;
            if (b == 0)      gb = tv[1] - tv[0];
            else if (b == 7) gb = tv[7] - tv[6];
            else             gb = (tv[b+1] - tv[b-1]) * 0.5f;
            acc += (double)fabsf(gb);
        }
        sred[t] = acc;
        __syncthreads();
        for (int off = 128; off > 0; off >>= 1) {
            if (t < off) sred[t] += sred[t + off];
            __syncthreads();
        }
        if (t == 0) dws[16 + aid] = sred[0];
    }
}

__global__ __launch_bounds__(256) void finalize_kernel(
    const float* __restrict__ vis, const float* __restrict__ txt, const float* __restrict__ gen,
    const float* __restrict__ Wv, const float* __restrict__ bv,
    const float* __restrict__ Wt, const float* __restrict__ bt,
    const float* __restrict__ Wg, const float* __restrict__ bg,
    const float* __restrict__ wsf, const double* __restrict__ dws,
    float* __restrict__ out)
{
    __shared__ double sphi[24];     // phi[m][b], m: 0=v 1=t 2=g
    __shared__ double sred[256];
    __shared__ double s_sumv, s_sumt, s_sumw;
    const int t = threadIdx.x;

    if (t < 24) {
        const int m = t >> 3, b = t & 7;
        const int nch = (m == 1) ? 32 : 16;
        const float* base = wsf + ((m == 0) ? 0 : (m == 1) ? 512 : 1536) + (size_t)b * nch * 4;
        QD p = { (double)base[0], (double)base[1], (double)base[2], (double)base[3] };
        for (int c = 1; c < nch; ++c) {
            QD o = { (double)base[c*4], (double)base[c*4+1], (double)base[c*4+2], (double)base[c*4+3] };
            p = qmuld(p, o);
        }
        // q0 = normalized first quaternion of the path
        float lat[4];
        if (m == 0) {
            const float x0 = vis[(size_t)b*HW*3], x1 = vis[(size_t)b*HW*3+1], x2 = vis[(size_t)b*HW*3+2];
            #pragma unroll
            for (int c = 0; c < 4; ++c)
                lat[c] = fmaf(x0, Wv[c], fmaf(x1, Wv[DD+c], fmaf(x2, Wv[2*DD+c], bv[c])));
        } else if (m == 1) {
            const float x0 = txt[(size_t)b*LTXT];
            #pragma unroll
            for (int c = 0; c < 4; ++c) lat[c] = fmaf(x0, Wt[c], bt[c]);
        } else {
            const float x0 = gen[(size_t)b*GG*4], x1 = gen[(size_t)b*GG*4+1],
                        x2 = gen[(size_t)b*GG*4+2], x3 = gen[(size_t)b*GG*4+3];
            #pragma unroll
            for (int c = 0; c < 4; ++c)
                lat[c] = fmaf(x0, Wg[c], fmaf(x1, Wg[DD+c], fmaf(x2, Wg[2*DD+c], fmaf(x3, Wg[3*DD+c], bg[c]))));
        }
        QF q0f = qnorm_f32(lat[0], lat[1], lat[2], lat[3]);
        QD q0 = { (double)q0f.w, (double)q0f.x, (double)q0f.y, (double)q0f.z };
        p = qmuld(p, q0);
        double w = p.w;
        if (w > 1.0) w = 1.0;
        if (w < -1.0) w = -1.0;
        sphi[t] = 2.0 * acos(w);
    }
    __syncthreads();

    // vision audit sum (16 partials)
    sred[t] = (t < 16) ? dws[t] : 0.0; __syncthreads();
    for (int off = 128; off > 0; off >>= 1) { if (t < off) sred[t] += sred[t+off]; __syncthreads(); }
    if (t == 0) s_sumv = sred[0];
    __syncthreads();

    // text audit sum (32 partials)
    sred[t] = (t < 32) ? dws[16 + t] : 0.0; __syncthreads();
    for (int off = 128; off > 0; off >>= 1) { if (t < off) sred[t] += sred[t+off]; __syncthreads(); }
    if (t == 0) s_sumt = sred[0];
    __syncthreads();

    // sum_i |wtq_i|, wtq_i = sum of 4 consecutive Wt entries
    double aw = 0.0;
    if (t < 64) {
        const int d0 = 4 * t;
        aw = (double)fabsf(Wt[d0] + Wt[d0+1] + Wt[d0+2] + Wt[d0+3]);
    }
    sred[t] = aw; __syncthreads();
    for (int off = 128; off > 0; off >>= 1) { if (t < off) sred[t] += sred[t+off]; __syncthreads(); }
    if (t == 0) s_sumw = sred[0];
    __syncthreads();

    if (t == 0) {
        double mv = 0.0, mt = 0.0;
        for (int b = 0; b < 8; ++b) { mv += sphi[b]; mt += sphi[8 + b]; }
        mv /= 8.0; mt /= 8.0;
        const double interf = fabs(mv - mt);
        for (int b = 0; b < 8; ++b)
            out[b] = (float)exp(-fabs(sphi[16 + b] - interf));
        out[8]  = (float)interf;
        out[9]  = (float)(s_sumv / 2097152.0);            // 8 * 262144
        out[10] = (float)(s_sumt * s_sumw / 4194304.0);   // 8 * 524288
    }
}

extern "C" void kernel_launch(void* const* d_in, const int* in_sizes, int n_in,
                              void* d_out, int out_size, void* d_ws, size_t ws_size,
                              hipStream_t stream) {
    (void)in_sizes; (void)n_in; (void)out_size; (void)ws_size;
    const float* vis = (const float*)d_in[0];
    const float* txt = (const float*)d_in[1];
    const float* gen = (const float*)d_in[2];
    const float* Wv  = (const float*)d_in[3];
    const float* bv  = (const float*)d_in[4];
    const float* Wt  = (const float*)d_in[5];
    const float* bt  = (const float*)d_in[6];
    const float* Wg  = (const float*)d_in[7];
    const float* bg  = (const float*)d_in[8];
    float*  wsf = (float*)d_ws;
    double* dws = (double*)((char*)d_ws + 8192);
    float*  out = (float*)d_out;

    hipLaunchKernelGGL(worker_kernel, dim3(560), dim3(256), 0, stream,
                       vis, txt, gen, Wv, bv, Wt, bt, Wg, bg, wsf, dws);
    hipLaunchKernelGGL(finalize_kernel, dim3(1), dim3(256), 0, stream,
                       vis, txt, gen, Wv, bv, Wt, bt, Wg, bg, wsf, dws, out);
}